// Round 9
// baseline (1291.880 us; speedup 1.0000x reference)
//
#include <hip/hip_runtime.h>
#include <hip/hip_bf16.h>
#include <cstddef>

#define CC 1024   // states
#define HH 256    // hidden
#define VV 10000  // vocab
#define NN 16     // batch
#define TT 256    // time
#define NB 16     // blocks in k_fwd
#define NVB 40    // v-tiles in k_emitg

typedef __attribute__((ext_vector_type(8))) short s8b;
typedef __attribute__((ext_vector_type(4))) float f32x4;
typedef __attribute__((ext_vector_type(4))) unsigned int u32x4;

__device__ __forceinline__ unsigned short f2bf(float f) {
    unsigned int b = __builtin_bit_cast(unsigned int, f);
    b += 0x7FFFu + ((b >> 16) & 1u);
    return (unsigned short)(b >> 16);
}
__device__ __forceinline__ float bf2f(unsigned short u) {
    return __builtin_bit_cast(float, ((unsigned int)u) << 16);
}

// ---------------- residual MLP ----------------
struct ResArgs { const float *x, *w1, *b1, *w2, *b2; float* o; };
struct ResArgs3 { ResArgs a[3]; };

__global__ __launch_bounds__(256) void k_res(ResArgs3 A)
{
    ResArgs R = A.a[blockIdx.y];
    const int r0 = blockIdx.x * 16;
    const int th = threadIdx.x;
    __shared__ float xs[256][24];
    __shared__ float hs[256][24];
    #pragma unroll
    for (int k = 0; k < 16; k++) xs[th][k] = R.x[(size_t)(r0 + k) * HH + th];
    __syncthreads();
    float acc[16];
    float b1v = R.b1[th];
    #pragma unroll
    for (int r = 0; r < 16; r++) acc[r] = b1v;
    for (int h = 0; h < HH; h++) {
        float w = R.w1[(size_t)h * HH + th];
        #pragma unroll
        for (int r = 0; r < 16; r++) acc[r] = fmaf(xs[h][r], w, acc[r]);
    }
    #pragma unroll
    for (int r = 0; r < 16; r++) hs[th][r] = fmaxf(acc[r], 0.f);
    __syncthreads();
    float b2v = R.b2[th];
    #pragma unroll
    for (int r = 0; r < 16; r++) acc[r] = b2v;
    for (int h = 0; h < HH; h++) {
        float w = R.w2[(size_t)h * HH + th];
        #pragma unroll
        for (int r = 0; r < 16; r++) acc[r] = fmaf(hs[h][r], w, acc[r]);
    }
    #pragma unroll
    for (int r = 0; r < 16; r++) {
        size_t idx = (size_t)(r0 + r) * HH + th;
        R.o[idx] = fmaxf(acc[r], 0.f) + R.x[idx];
    }
}

// ---------------- start logits ----------------
__global__ __launch_bounds__(256) void k_slog(const float* __restrict__ res_s,
                                              const float* __restrict__ sw3,
                                              const float* __restrict__ sb3,
                                              float* __restrict__ slog)
{
    __shared__ float wv[256];
    const int th = threadIdx.x;
    const int c = blockIdx.x * 256 + th;
    wv[th] = sw3[th];
    __syncthreads();
    const float* row = res_s + (size_t)c * HH;
    float acc = 0.f;
    for (int h = 0; h < HH; h++) acc = fmaf(row[h], wv[h], acc);
    slog[c] = acc + sb3[0];
}

// ---------------- transition probs, transposed bf16: PB[j][i] = p(j | i) ----------------
__global__ __launch_bounds__(256) void k_pt(const float* __restrict__ res_t,
                                            const float* __restrict__ tw3,
                                            const float* __restrict__ tb3,
                                            unsigned short* __restrict__ PB)
{
    const int r0 = blockIdx.x * 4;
    const int th = threadIdx.x;
    __shared__ float rs[4][256];
    __shared__ float sred[256];
    for (int k = 0; k < 4; k++) rs[k][th] = res_t[(size_t)(r0 + k) * HH + th];
    __syncthreads();
    float acc[4][4];
    #pragma unroll
    for (int r = 0; r < 4; r++)
        #pragma unroll
        for (int q = 0; q < 4; q++) acc[r][q] = tb3[th + q * 256];
    for (int h = 0; h < HH; h++) {
        float w0 = tw3[(size_t)h * CC + th];
        float w1 = tw3[(size_t)h * CC + th + 256];
        float w2 = tw3[(size_t)h * CC + th + 512];
        float w3 = tw3[(size_t)h * CC + th + 768];
        #pragma unroll
        for (int r = 0; r < 4; r++) {
            float xv = rs[r][h];
            acc[r][0] = fmaf(xv, w0, acc[r][0]);
            acc[r][1] = fmaf(xv, w1, acc[r][1]);
            acc[r][2] = fmaf(xv, w2, acc[r][2]);
            acc[r][3] = fmaf(xv, w3, acc[r][3]);
        }
    }
    for (int r = 0; r < 4; r++) {
        float m = fmaxf(fmaxf(acc[r][0], acc[r][1]), fmaxf(acc[r][2], acc[r][3]));
        sred[th] = m; __syncthreads();
        for (int off = 128; off > 0; off >>= 1) { if (th < off) sred[th] = fmaxf(sred[th], sred[th + off]); __syncthreads(); }
        float rm = sred[0]; __syncthreads();
        float ssum = __expf(acc[r][0] - rm) + __expf(acc[r][1] - rm) + __expf(acc[r][2] - rm) + __expf(acc[r][3] - rm);
        sred[th] = ssum; __syncthreads();
        for (int off = 128; off > 0; off >>= 1) { if (th < off) sred[th] += sred[th + off]; __syncthreads(); }
        float inv = 1.0f / sred[0]; __syncthreads();
        #pragma unroll
        for (int q = 0; q < 4; q++) {
            float p = __expf(acc[r][q] - rm) * inv;
            PB[(size_t)(th + q * 256) * CC + (r0 + r)] = f2bf(p);   // [j][i]
        }
    }
}

// ---------------- emission logits via MFMA GEMM + fused LSE partials ----------------
__global__ __launch_bounds__(256) void k_emitg(const float* __restrict__ res_e,
                                               const float* __restrict__ ew3,
                                               const float* __restrict__ eb3,
                                               unsigned short* __restrict__ emitT,
                                               float* __restrict__ epart2)
{
    const int vb = blockIdx.x, c0 = blockIdx.y * 64;
    const int th = threadIdx.x;
    const int w = th >> 6, l = th & 63;
    const int lhi = l >> 4, llo = l & 15;
    const int wv = w & 1, wc = w >> 1;

    __shared__ __align__(16) unsigned short ewT[64 * 256];
    __shared__ __align__(16) unsigned short rsb[64 * 256];
    __shared__ float ebl[64];
    __shared__ float wlse[4][2][16][2];

    {
        char* base = (char*)rsb;
        #pragma unroll
        for (int i = 0; i < 8; i++) {
            int g = i * 2048 + th * 8;
            int row = g >> 8, h0 = g & 255;
            const float* src = res_e + (size_t)(c0 + row) * HH + h0;
            float4 f0 = *(const float4*)(src);
            float4 f1 = *(const float4*)(src + 4);
            s8b pk;
            pk[0] = (short)f2bf(f0.x); pk[1] = (short)f2bf(f0.y);
            pk[2] = (short)f2bf(f0.z); pk[3] = (short)f2bf(f0.w);
            pk[4] = (short)f2bf(f1.x); pk[5] = (short)f2bf(f1.y);
            pk[6] = (short)f2bf(f1.z); pk[7] = (short)f2bf(f1.w);
            *(s8b*)(base + row * 512 + ((h0 * 2) ^ ((row & 7) << 4))) = pk;
        }
    }

    float rM = -1e30f, rS = 0.f;

    for (int r = 0; r < 4; r++) {
        const int v0r = vb * 256 + r * 64;
        __syncthreads();
        {
            int tv = th & 63;
            char* base = (char*)ewT;
            int rowoff = tv * 512;
            int key = (tv & 7) << 4;
            int vglob = v0r + tv;
            bool valid = vglob < VV;
            #pragma unroll 8
            for (int i = 0; i < 64; i++) {
                int h = (th >> 6) + i * 4;
                float x = valid ? ew3[(size_t)h * VV + vglob] : 0.f;
                *(unsigned short*)(base + rowoff + ((h * 2) ^ key)) = f2bf(x);
            }
        }
        if (th < 64) ebl[th] = (v0r + th < VV) ? eb3[v0r + th] : 0.f;
        __syncthreads();

        f32x4 acc[2][2] = {{{0,0,0,0},{0,0,0,0}},{{0,0,0,0},{0,0,0,0}}};
        const char* ea = (const char*)ewT;
        const char* rb = (const char*)rsb;
        const int arow0 = wv * 32 + llo, arow1 = wv * 32 + 16 + llo;
        const int brow0 = wc * 32 + llo, brow1 = wc * 32 + 16 + llo;
        const int akey0 = (arow0 & 7) << 4;
        const int bkey0 = (brow0 & 7) << 4;
        #pragma unroll
        for (int kt = 0; kt < 8; kt++) {
            int off = kt * 64 + lhi * 16;
            s8b a0 = *(const s8b*)(ea + arow0 * 512 + (off ^ akey0));
            s8b a1 = *(const s8b*)(ea + arow1 * 512 + (off ^ akey0));
            s8b b0 = *(const s8b*)(rb + brow0 * 512 + (off ^ bkey0));
            s8b b1 = *(const s8b*)(rb + brow1 * 512 + (off ^ bkey0));
            acc[0][0] = __builtin_amdgcn_mfma_f32_16x16x32_bf16(a0, b0, acc[0][0], 0, 0, 0);
            acc[0][1] = __builtin_amdgcn_mfma_f32_16x16x32_bf16(a0, b1, acc[0][1], 0, 0, 0);
            acc[1][0] = __builtin_amdgcn_mfma_f32_16x16x32_bf16(a1, b0, acc[1][0], 0, 0, 0);
            acc[1][1] = __builtin_amdgcn_mfma_f32_16x16x32_bf16(a1, b1, acc[1][1], 0, 0, 0);
        }

        float um[2], us[2];
        #pragma unroll
        for (int u = 0; u < 2; u++) {
            float vals[8];
            #pragma unroll
            for (int s = 0; s < 2; s++) {
                #pragma unroll
                for (int q = 0; q < 4; q++) {
                    int vloc = wv * 32 + s * 16 + lhi * 4 + q;
                    int vglob = v0r + vloc;
                    float logit = acc[s][u][q] + ebl[vloc];
                    bool valid = vglob < VV;
                    if (valid)
                        emitT[(size_t)vglob * CC + (c0 + wc * 32 + u * 16 + llo)] = f2bf(logit);
                    vals[s * 4 + q] = valid ? logit : -1e30f;
                }
            }
            float m = vals[0];
            #pragma unroll
            for (int e = 1; e < 8; e++) m = fmaxf(m, vals[e]);
            float ss = 0.f;
            #pragma unroll
            for (int e = 0; e < 8; e++) ss += __expf(vals[e] - m);
            #pragma unroll
            for (int o = 16; o < 64; o <<= 1) {
                float m2 = __shfl_xor(m, o);
                float s2 = __shfl_xor(ss, o);
                float nm = fmaxf(m, m2);
                ss = ss * __expf(m - nm) + s2 * __expf(m2 - nm);
                m = nm;
            }
            um[u] = m; us[u] = ss;
        }
        if (l < 16) {
            #pragma unroll
            for (int u = 0; u < 2; u++) {
                wlse[w][u][l][0] = um[u];
                wlse[w][u][l][1] = us[u];
            }
        }
        __syncthreads();
        if (th < 64) {
            int wc2 = th >> 5, u2 = (th >> 4) & 1, ll2 = th & 15;
            float m1 = wlse[2 * wc2][u2][ll2][0], s1 = wlse[2 * wc2][u2][ll2][1];
            float m2 = wlse[2 * wc2 + 1][u2][ll2][0], s2 = wlse[2 * wc2 + 1][u2][ll2][1];
            float nm = fmaxf(m1, m2);
            float ns = s1 * __expf(m1 - nm) + s2 * __expf(m2 - nm);
            float fm = fmaxf(rM, nm);
            rS = rS * __expf(rM - fm) + ns * __expf(nm - fm);
            rM = fm;
        }
    }
    if (th < 64) {
        epart2[((size_t)vb * CC + c0 + th) * 2]     = rM;
        epart2[((size_t)vb * CC + c0 + th) * 2 + 1] = rS;
    }
}

// ---------------- combine epart2 -> lse[c] ----------------
__global__ __launch_bounds__(256) void k_lse(const float* __restrict__ epart2,
                                             float* __restrict__ lse)
{
    int c = blockIdx.x * 256 + threadIdx.x;
    float M = -1e30f, S = 0.f;
    for (int vb = 0; vb < NVB; vb++) {
        float m  = epart2[((size_t)vb * CC + c) * 2];
        float s2 = epart2[((size_t)vb * CC + c) * 2 + 1];
        float nm = fmaxf(M, m);
        S = S * __expf(M - nm) + s2 * __expf(m - nm);
        M = nm;
    }
    lse[c] = M + __logf(S);
}

// ---------------- full-v load+stage (final reduction), R7-proven pattern ----------------
__device__ __forceinline__ void load_stage_full(const unsigned short* vbuf_t, int th, char* vl)
{
    const unsigned short* sb = vbuf_t + th * 8;
    s8b ch[8];
    #pragma unroll
    for (int c = 0; c < 8; c++)
        asm volatile("global_load_dwordx4 %0, %1, off sc0 sc1"
                     : "=v"(ch[c]) : "v"(sb + c * 2048));
    asm volatile("s_waitcnt vmcnt(0)" ::: "memory");
    __builtin_amdgcn_sched_barrier(0);
    for (;;) {
        unsigned int miss = 0u;
        #pragma unroll
        for (int c = 0; c < 8; c++) {
            u32x4 d = __builtin_bit_cast(u32x4, ch[c]);
            if (d[0] == 0xFFFFFFFFu || d[1] == 0xFFFFFFFFu ||
                d[2] == 0xFFFFFFFFu || d[3] == 0xFFFFFFFFu) miss |= 1u << c;
        }
        if (!__any(miss != 0u)) break;
        #pragma unroll
        for (int c = 0; c < 8; c++)
            if (miss & (1u << c))
                asm volatile("global_load_dwordx4 %0, %1, off sc0 sc1"
                             : "=v"(ch[c]) : "v"(sb + c * 2048));
        asm volatile("s_waitcnt vmcnt(0)" ::: "memory");
        __builtin_amdgcn_sched_barrier(0);
    }
    #pragma unroll
    for (int c = 0; c < 8; c++) {
        int ow = c * 4096 + th * 16;
        *(s8b*)(vl + (ow ^ (((ow >> 11) & 7) << 4))) = ch[c];
    }
}

// ---------------- forward scan: 2-group interleaved pipeline ----------------
// Groups: G0 = seq 0-7, G1 = seq 8-15. Phase ph: g = ph&1, t = ph/2+1.
// Phase body: collect pend (issued one phase earlier) -> stage to LDS half ->
// issue epf + next pend -> MFMA(M=8, dup rows) -> vmcnt(4) -> epilogue ->
// publish. Exchange latency hides under the other group's phase.
__global__ void __launch_bounds__(256, 1) k_fwd(
    const unsigned short* __restrict__ PB,    // [1024 j][1024 i] bf16
    const unsigned short* __restrict__ emitT, // [V][1024 c] bf16 LOGITS
    const float* __restrict__ lse,            // [1024]
    const float* __restrict__ slog,
    const int* __restrict__ text,
    unsigned short* vbuf,                     // [TT][NN][CC] bf16, sentinel-armed
    float* __restrict__ outp)
{
    const int blk = blockIdx.x;
    const int th = threadIdx.x;
    const int w = th >> 6, l = th & 63;
    const int lhi = l >> 4, llo = l & 15;
    const int jglob = blk * 64 + w * 16 + llo;

    __shared__ int toks[NN * TT];                              // 16 KB
    __shared__ __align__(16) unsigned short vlds[NN * CC];     // 32 KB (two 16 KB halves)
    __shared__ __align__(16) unsigned short vtile[16][72];
    __shared__ float swk[4];
    __shared__ float sfin[16];
    __shared__ float fin[16];

    for (int i = th; i < NN * TT; i += 256) toks[i] = text[i];

    // B fragments resident in regs
    s8b bfr[32];
    {
        const unsigned short* pbj = PB + (size_t)jglob * CC + lhi * 8;
        #pragma unroll
        for (int kt = 0; kt < 32; kt++)
            bfr[kt] = *(const s8b*)(pbj + kt * 32);
    }
    s8b ones;
    #pragma unroll
    for (int e = 0; e < 8; e++) ones[e] = (short)0x3F80;

    const float lse_j = lse[jglob];

    // block-wide LSE of slog
    float x0 = slog[th], x1 = slog[th + 256], x2 = slog[th + 512], x3 = slog[th + 768];
    float mw = fmaxf(fmaxf(x0, x1), fmaxf(x2, x3));
    #pragma unroll
    for (int o = 32; o; o >>= 1) mw = fmaxf(mw, __shfl_xor(mw, o));
    __syncthreads();   // toks ready
    if (l == 0) swk[w] = mw;
    __syncthreads();
    float gm = fmaxf(fmaxf(swk[0], swk[1]), fmaxf(swk[2], swk[3]));
    __syncthreads();
    float e4 = __expf(x0 - gm) + __expf(x1 - gm) + __expf(x2 - gm) + __expf(x3 - gm);
    #pragma unroll
    for (int o = 32; o; o >>= 1) e4 += __shfl_xor(e4, o);
    if (l == 0) swk[w] = e4;
    __syncthreads();
    float slse = gm + __logf(swk[0] + swk[1] + swk[2] + swk[3]);
    __syncthreads();

    // ---- t = 0 ----
    if (th < 64) {
        int jj = blk * 64 + th;
        float p0 = __expf(slog[jj] - slse);
        float lsej = lse[jj];
        #pragma unroll
        for (int n = 0; n < 16; n++)
            vtile[n][th] = f2bf(p0 * __expf(bf2f(emitT[(size_t)toks[n * TT] * CC + jj]) - lsej));
    }
    __syncthreads();
    if (th < 128) {
        int n = th >> 3, seg = th & 7;
        s8b val = *(const s8b*)&vtile[n][seg * 8];
        unsigned short* dst = vbuf + (size_t)n * CC + blk * 64 + seg * 8;
        asm volatile("global_store_dwordx4 %0, %1, off sc0 sc1" :: "v"(dst), "v"(val) : "memory");
    }

    // issue pend for phase 0 (G0, slot 0)
    s8b pend[4];
    {
        const unsigned short* pb = vbuf + th * 8;   // slot 0, g=0
        #pragma unroll
        for (int c = 0; c < 4; c++)
            asm volatile("global_load_dwordx4 %0, %1, off sc0 sc1"
                         : "=v"(pend[c]) : "v"(pb + c * 2048));
    }

    float logA[4] = {0,0,0,0}, logB[4] = {0,0,0,0};
    char* vl = (char*)vlds;
    const int rkey = (llo & 7) << 4;

    for (int ph = 0; ph < 510; ph++) {
        const int g = ph & 1, t = (ph >> 1) + 1, slot = t - 1;

        // ---- collect pend (drains pend + prior stores) ----
        asm volatile("s_waitcnt vmcnt(0)" ::: "memory");
        __builtin_amdgcn_sched_barrier(0);
        {
            const unsigned short* pb = vbuf + (size_t)slot * (NN * CC) + g * 8192 + th * 8;
            for (;;) {
                unsigned int miss = 0u;
                #pragma unroll
                for (int c = 0; c < 4; c++) {
                    u32x4 d = __builtin_bit_cast(u32x4, pend[c]);
                    if (d[0] == 0xFFFFFFFFu || d[1] == 0xFFFFFFFFu ||
                        d[2] == 0xFFFFFFFFu || d[3] == 0xFFFFFFFFu) miss |= 1u << c;
                }
                if (!__any(miss != 0u)) break;
                #pragma unroll
                for (int c = 0; c < 4; c++)
                    if (miss & (1u << c))
                        asm volatile("global_load_dwordx4 %0, %1, off sc0 sc1"
                                     : "=v"(pend[c]) : "v"(pb + c * 2048));
                asm volatile("s_waitcnt vmcnt(0)" ::: "memory");
                __builtin_amdgcn_sched_barrier(0);
            }
        }

        // ---- stage into LDS half g ----
        #pragma unroll
        for (int c = 0; c < 4; c++) {
            int ow = g * 16384 + th * 16 + c * 4096;
            *(s8b*)(vl + (ow ^ (((ow >> 11) & 7) << 4))) = pend[c];
        }

        // ---- issue emission-logit gathers (uniform; 4 oldest vmem ops) ----
        unsigned int epfu[4];
        #pragma unroll
        for (int q = 0; q < 4; q++) {
            int r = (lhi * 4 + q) & 7;
            const unsigned short* ep = emitT + (size_t)toks[(g * 8 + r) * TT + t] * CC + jglob;
            asm volatile("global_load_ushort %0, %1, off" : "=v"(epfu[q]) : "v"(ep));
        }
        __syncthreads();   // vlds half g ready

        // ---- issue pend for next phase (4 newest vmem ops, fly across MFMA) ----
        if (ph < 509) {
            const int g2 = (ph + 1) & 1, s2 = (ph + 1) >> 1;
            const unsigned short* pb2 = vbuf + (size_t)s2 * (NN * CC) + g2 * 8192 + th * 8;
            #pragma unroll
            for (int c = 0; c < 4; c++)
                asm volatile("global_load_dwordx4 %0, %1, off sc0 sc1"
                             : "=v"(pend[c]) : "v"(pb2 + c * 2048));
        }

        // ---- MFMA (M=8; rows 8-15 duplicate rows 0-7) ----
        const int rbase = (g * 8 + (llo & 7)) * 2048 + lhi * 16;
        f32x4 ac0 = {0,0,0,0}, ac1 = {0,0,0,0}, ac2 = {0,0,0,0}, ac3 = {0,0,0,0};
        f32x4 ao0 = {0,0,0,0}, ao1 = {0,0,0,0};
        #pragma unroll
        for (int kt = 0; kt < 32; kt += 4) {
            s8b a0 = *(const s8b*)(vl + ((rbase + (kt + 0) * 64) ^ rkey));
            s8b a1 = *(const s8b*)(vl + ((rbase + (kt + 1) * 64) ^ rkey));
            s8b a2 = *(const s8b*)(vl + ((rbase + (kt + 2) * 64) ^ rkey));
            s8b a3 = *(const s8b*)(vl + ((rbase + (kt + 3) * 64) ^ rkey));
            ac0 = __builtin_amdgcn_mfma_f32_16x16x32_bf16(a0, bfr[kt + 0], ac0, 0, 0, 0);
            ao0 = __builtin_amdgcn_mfma_f32_16x16x32_bf16(a0, ones,        ao0, 0, 0, 0);
            ac1 = __builtin_amdgcn_mfma_f32_16x16x32_bf16(a1, bfr[kt + 1], ac1, 0, 0, 0);
            ao1 = __builtin_amdgcn_mfma_f32_16x16x32_bf16(a1, ones,        ao1, 0, 0, 0);
            ac2 = __builtin_amdgcn_mfma_f32_16x16x32_bf16(a2, bfr[kt + 2], ac2, 0, 0, 0);
            ao0 = __builtin_amdgcn_mfma_f32_16x16x32_bf16(a2, ones,        ao0, 0, 0, 0);
            ac3 = __builtin_amdgcn_mfma_f32_16x16x32_bf16(a3, bfr[kt + 3], ac3, 0, 0, 0);
            ao1 = __builtin_amdgcn_mfma_f32_16x16x32_bf16(a3, ones,        ao1, 0, 0, 0);
        }
        f32x4 acc = (ac0 + ac1) + (ac2 + ac3);
        f32x4 aco = ao0 + ao1;   // S for rows (duplicated into 8-15)

        // ---- wait emission gathers only (keep next pend flying) ----
        if (ph < 509) { asm volatile("s_waitcnt vmcnt(4)" ::: "memory"); }
        else          { asm volatile("s_waitcnt vmcnt(0)" ::: "memory"); }
        __builtin_amdgcn_sched_barrier(0);

        // ---- epilogue: rows 0-7 via lhi<2 lanes ----
        if (lhi < 2) {
            #pragma unroll
            for (int q = 0; q < 4; q++) {
                int r = lhi * 4 + q;
                float S = aco[q];
                float lg = __logf(S);
                if (g == 0) logA[q] += lg; else logB[q] += lg;
                float ep = __expf(bf2f((unsigned short)epfu[q]) - lse_j);
                float vq = acc[q] * (1.0f / S) * ep;
                vtile[r][w * 16 + llo] = f2bf(vq);
            }
        }
        __syncthreads();

        // ---- publish group slice (8 n x 64 j) ----
        if (th < 64) {
            int n = th >> 3, seg = th & 7;
            s8b val = *(const s8b*)&vtile[n][seg * 8];
            unsigned short* dst = vbuf + (size_t)t * (NN * CC) + (size_t)(g * 8 + n) * CC + blk * 64 + seg * 8;
            asm volatile("global_store_dwordx4 %0, %1, off sc0 sc1" :: "v"(dst), "v"(val) : "memory");
        }
    }

    // ---- final: block 0 computes S_255 for all 16 n ----
    if (blk == 0) {
        load_stage_full(vbuf + (size_t)255 * (NN * CC), th, vl);
        __syncthreads();
        const int rbaseF = llo * 2048 + lhi * 16;
        f32x4 fo0 = {0,0,0,0}, fo1 = {0,0,0,0};
        #pragma unroll
        for (int kt = 0; kt < 32; kt += 2) {
            s8b a0 = *(const s8b*)(vl + ((rbaseF + (kt + 0) * 64) ^ rkey));
            s8b a1 = *(const s8b*)(vl + ((rbaseF + (kt + 1) * 64) ^ rkey));
            fo0 = __builtin_amdgcn_mfma_f32_16x16x32_bf16(a0, ones, fo0, 0, 0, 0);
            fo1 = __builtin_amdgcn_mfma_f32_16x16x32_bf16(a1, ones, fo1, 0, 0, 0);
        }
        f32x4 acoF = fo0 + fo1;
        if (w == 0 && llo == 0) {
            #pragma unroll
            for (int q = 0; q < 4; q++) sfin[lhi * 4 + q] = acoF[q];
        }
        __syncthreads();
        if (w == 0 && llo == 0 && lhi < 2) {
            #pragma unroll
            for (int q = 0; q < 4; q++) {
                int r = lhi * 4 + q;
                fin[r]     = logA[q] + __logf(sfin[r]);
                fin[8 + r] = logB[q] + __logf(sfin[8 + r]);
            }
        }
        __syncthreads();
        if (th == 0) {
            float tot = 0.f;
            for (int n = 0; n < 16; n++) tot += fin[n];
            outp[0] = tot;
        }
    }
}

extern "C" void kernel_launch(void* const* d_in, const int* in_sizes, int n_in,
                              void* d_out, int out_size, void* d_ws, size_t ws_size,
                              hipStream_t stream) {
    const int*   text      = (const int*)  d_in[0];
    const float* start_emb = (const float*)d_in[1];
    const float* sw1 = (const float*)d_in[2];
    const float* sb1 = (const float*)d_in[3];
    const float* sw2 = (const float*)d_in[4];
    const float* sb2 = (const float*)d_in[5];
    const float* sw3 = (const float*)d_in[6];
    const float* sb3 = (const float*)d_in[7];
    const float* state_emb = (const float*)d_in[8];
    const float* tw1 = (const float*)d_in[9];
    const float* tb1 = (const float*)d_in[10];
    const float* tw2 = (const float*)d_in[11];
    const float* tb2 = (const float*)d_in[12];
    const float* tw3 = (const float*)d_in[13];
    const float* tb3 = (const float*)d_in[14];
    const float* pre_emb = (const float*)d_in[15];
    const float* ew1 = (const float*)d_in[16];
    const float* eb1 = (const float*)d_in[17];
    const float* ew2 = (const float*)d_in[18];
    const float* eb2 = (const float*)d_in[19];
    const float* ew3 = (const float*)d_in[20];
    const float* eb3 = (const float*)d_in[21];

    char* wsp = (char*)d_ws;
    // layout (bytes):
    //   PB     [0, 2 MiB)
    //   emitT  [2 MiB, 22,577,152)
    //   res_s  [2 MiB, 3 MiB)    \ overlay emitT head: dead before k_emitg writes
    //   res_t  [3 MiB, 4 MiB)    /
    //   res_e  [22,577,152, 23,625,728)
    //   slog   [23,625,728, +4 KiB)
    //   lse    [23,629,824, +4 KiB)
    //   epart2 [23,633,920, +320 KiB)
    //   vbuf   [23 MiB, 31 MiB) sentinel-armed
    unsigned short* PB    = (unsigned short*)(wsp);
    unsigned short* emitT = (unsigned short*)(wsp + ((size_t)2 << 20));
    float* res_s = (float*)(wsp + ((size_t)2 << 20));
    float* res_t = (float*)(wsp + ((size_t)3 << 20));
    float* res_e = (float*)(wsp + 22577152u);
    float* slog  = (float*)(wsp + 23625728u);
    float* lse   = (float*)(wsp + 23629824u);
    float* epart2= (float*)(wsp + 23633920u);
    unsigned short* vbuf = (unsigned short*)(wsp + ((size_t)23 << 20));
    float* outp  = (float*)d_out;

    if (ws_size < ((size_t)31 << 20)) return;  // leaves poison -> visible failure

    hipMemsetAsync(vbuf, 0xFF, (size_t)TT * NN * CC * sizeof(unsigned short), stream);

    ResArgs3 ra;
    ra.a[0] = { start_emb, sw1, sb1, sw2, sb2, res_s };
    ra.a[1] = { state_emb, tw1, tb1, tw2, tb2, res_t };
    ra.a[2] = { pre_emb,   ew1, eb1, ew2, eb2, res_e };

    hipLaunchKernelGGL(k_res,   dim3(64, 3),   dim3(256), 0, stream, ra);
    hipLaunchKernelGGL(k_slog,  dim3(4),       dim3(256), 0, stream, res_s, sw3, sb3, slog);
    hipLaunchKernelGGL(k_pt,    dim3(256),     dim3(256), 0, stream, res_t, tw3, tb3, PB);
    hipLaunchKernelGGL(k_emitg, dim3(NVB, 16), dim3(256), 0, stream, res_e, ew3, eb3, emitT, epart2);
    hipLaunchKernelGGL(k_lse,   dim3(4),       dim3(256), 0, stream, epart2, lse);
    hipLaunchKernelGGL(k_fwd,   dim3(NB),      dim3(256), 0, stream,
                       PB, emitT, lse, slog, text, vbuf, outp);
}

// Round 10
// 957.744 us; speedup vs baseline: 1.3489x; 1.3489x over previous
//
#include <hip/hip_runtime.h>
#include <hip/hip_bf16.h>
#include <cstddef>

#define CC 1024   // states
#define HH 256    // hidden
#define VV 10000  // vocab
#define NN 16     // batch
#define TT 256    // time
#define NB 16     // blocks in k_fwd
#define NVB 40    // v-tiles in k_emitg

typedef __attribute__((ext_vector_type(8))) short s8b;
typedef __attribute__((ext_vector_type(4))) float f32x4;
typedef __attribute__((ext_vector_type(4))) unsigned int u32x4;

__device__ __forceinline__ unsigned short f2bf(float f) {
    unsigned int b = __builtin_bit_cast(unsigned int, f);
    b += 0x7FFFu + ((b >> 16) & 1u);
    return (unsigned short)(b >> 16);
}
__device__ __forceinline__ float bf2f(unsigned short u) {
    return __builtin_bit_cast(float, ((unsigned int)u) << 16);
}

// ---------------- residual MLP ----------------
struct ResArgs { const float *x, *w1, *b1, *w2, *b2; float* o; };
struct ResArgs3 { ResArgs a[3]; };

__global__ __launch_bounds__(256) void k_res(ResArgs3 A)
{
    ResArgs R = A.a[blockIdx.y];
    const int r0 = blockIdx.x * 16;
    const int th = threadIdx.x;
    __shared__ float xs[256][24];
    __shared__ float hs[256][24];
    #pragma unroll
    for (int k = 0; k < 16; k++) xs[th][k] = R.x[(size_t)(r0 + k) * HH + th];
    __syncthreads();
    float acc[16];
    float b1v = R.b1[th];
    #pragma unroll
    for (int r = 0; r < 16; r++) acc[r] = b1v;
    for (int h = 0; h < HH; h++) {
        float w = R.w1[(size_t)h * HH + th];
        #pragma unroll
        for (int r = 0; r < 16; r++) acc[r] = fmaf(xs[h][r], w, acc[r]);
    }
    #pragma unroll
    for (int r = 0; r < 16; r++) hs[th][r] = fmaxf(acc[r], 0.f);
    __syncthreads();
    float b2v = R.b2[th];
    #pragma unroll
    for (int r = 0; r < 16; r++) acc[r] = b2v;
    for (int h = 0; h < HH; h++) {
        float w = R.w2[(size_t)h * HH + th];
        #pragma unroll
        for (int r = 0; r < 16; r++) acc[r] = fmaf(hs[h][r], w, acc[r]);
    }
    #pragma unroll
    for (int r = 0; r < 16; r++) {
        size_t idx = (size_t)(r0 + r) * HH + th;
        R.o[idx] = fmaxf(acc[r], 0.f) + R.x[idx];
    }
}

// ---------------- start logits ----------------
__global__ __launch_bounds__(256) void k_slog(const float* __restrict__ res_s,
                                              const float* __restrict__ sw3,
                                              const float* __restrict__ sb3,
                                              float* __restrict__ slog)
{
    __shared__ float wv[256];
    const int th = threadIdx.x;
    const int c = blockIdx.x * 256 + th;
    wv[th] = sw3[th];
    __syncthreads();
    const float* row = res_s + (size_t)c * HH;
    float acc = 0.f;
    for (int h = 0; h < HH; h++) acc = fmaf(row[h], wv[h], acc);
    slog[c] = acc + sb3[0];
}

// ---------------- transition probs, transposed bf16: PB[j][i] = p(j | i) ----------------
__global__ __launch_bounds__(256) void k_pt(const float* __restrict__ res_t,
                                            const float* __restrict__ tw3,
                                            const float* __restrict__ tb3,
                                            unsigned short* __restrict__ PB)
{
    const int r0 = blockIdx.x * 4;
    const int th = threadIdx.x;
    __shared__ float rs[4][256];
    __shared__ float sred[256];
    for (int k = 0; k < 4; k++) rs[k][th] = res_t[(size_t)(r0 + k) * HH + th];
    __syncthreads();
    float acc[4][4];
    #pragma unroll
    for (int r = 0; r < 4; r++)
        #pragma unroll
        for (int q = 0; q < 4; q++) acc[r][q] = tb3[th + q * 256];
    for (int h = 0; h < HH; h++) {
        float w0 = tw3[(size_t)h * CC + th];
        float w1 = tw3[(size_t)h * CC + th + 256];
        float w2 = tw3[(size_t)h * CC + th + 512];
        float w3 = tw3[(size_t)h * CC + th + 768];
        #pragma unroll
        for (int r = 0; r < 4; r++) {
            float xv = rs[r][h];
            acc[r][0] = fmaf(xv, w0, acc[r][0]);
            acc[r][1] = fmaf(xv, w1, acc[r][1]);
            acc[r][2] = fmaf(xv, w2, acc[r][2]);
            acc[r][3] = fmaf(xv, w3, acc[r][3]);
        }
    }
    for (int r = 0; r < 4; r++) {
        float m = fmaxf(fmaxf(acc[r][0], acc[r][1]), fmaxf(acc[r][2], acc[r][3]));
        sred[th] = m; __syncthreads();
        for (int off = 128; off > 0; off >>= 1) { if (th < off) sred[th] = fmaxf(sred[th], sred[th + off]); __syncthreads(); }
        float rm = sred[0]; __syncthreads();
        float ssum = __expf(acc[r][0] - rm) + __expf(acc[r][1] - rm) + __expf(acc[r][2] - rm) + __expf(acc[r][3] - rm);
        sred[th] = ssum; __syncthreads();
        for (int off = 128; off > 0; off >>= 1) { if (th < off) sred[th] += sred[th + off]; __syncthreads(); }
        float inv = 1.0f / sred[0]; __syncthreads();
        #pragma unroll
        for (int q = 0; q < 4; q++) {
            float p = __expf(acc[r][q] - rm) * inv;
            PB[(size_t)(th + q * 256) * CC + (r0 + r)] = f2bf(p);   // [j][i]
        }
    }
}

// ---------------- emission logits via MFMA GEMM + fused LSE partials ----------------
__global__ __launch_bounds__(256) void k_emitg(const float* __restrict__ res_e,
                                               const float* __restrict__ ew3,
                                               const float* __restrict__ eb3,
                                               unsigned short* __restrict__ emitT,
                                               float* __restrict__ epart2)
{
    const int vb = blockIdx.x, c0 = blockIdx.y * 64;
    const int th = threadIdx.x;
    const int w = th >> 6, l = th & 63;
    const int lhi = l >> 4, llo = l & 15;
    const int wv = w & 1, wc = w >> 1;

    __shared__ __align__(16) unsigned short ewT[64 * 256];
    __shared__ __align__(16) unsigned short rsb[64 * 256];
    __shared__ float ebl[64];
    __shared__ float wlse[4][2][16][2];

    {
        char* base = (char*)rsb;
        #pragma unroll
        for (int i = 0; i < 8; i++) {
            int g = i * 2048 + th * 8;
            int row = g >> 8, h0 = g & 255;
            const float* src = res_e + (size_t)(c0 + row) * HH + h0;
            float4 f0 = *(const float4*)(src);
            float4 f1 = *(const float4*)(src + 4);
            s8b pk;
            pk[0] = (short)f2bf(f0.x); pk[1] = (short)f2bf(f0.y);
            pk[2] = (short)f2bf(f0.z); pk[3] = (short)f2bf(f0.w);
            pk[4] = (short)f2bf(f1.x); pk[5] = (short)f2bf(f1.y);
            pk[6] = (short)f2bf(f1.z); pk[7] = (short)f2bf(f1.w);
            *(s8b*)(base + row * 512 + ((h0 * 2) ^ ((row & 7) << 4))) = pk;
        }
    }

    float rM = -1e30f, rS = 0.f;

    for (int r = 0; r < 4; r++) {
        const int v0r = vb * 256 + r * 64;
        __syncthreads();
        {
            int tv = th & 63;
            char* base = (char*)ewT;
            int rowoff = tv * 512;
            int key = (tv & 7) << 4;
            int vglob = v0r + tv;
            bool valid = vglob < VV;
            #pragma unroll 8
            for (int i = 0; i < 64; i++) {
                int h = (th >> 6) + i * 4;
                float x = valid ? ew3[(size_t)h * VV + vglob] : 0.f;
                *(unsigned short*)(base + rowoff + ((h * 2) ^ key)) = f2bf(x);
            }
        }
        if (th < 64) ebl[th] = (v0r + th < VV) ? eb3[v0r + th] : 0.f;
        __syncthreads();

        f32x4 acc[2][2] = {{{0,0,0,0},{0,0,0,0}},{{0,0,0,0},{0,0,0,0}}};
        const char* ea = (const char*)ewT;
        const char* rb = (const char*)rsb;
        const int arow0 = wv * 32 + llo, arow1 = wv * 32 + 16 + llo;
        const int brow0 = wc * 32 + llo, brow1 = wc * 32 + 16 + llo;
        const int akey0 = (arow0 & 7) << 4;
        const int bkey0 = (brow0 & 7) << 4;
        #pragma unroll
        for (int kt = 0; kt < 8; kt++) {
            int off = kt * 64 + lhi * 16;
            s8b a0 = *(const s8b*)(ea + arow0 * 512 + (off ^ akey0));
            s8b a1 = *(const s8b*)(ea + arow1 * 512 + (off ^ akey0));
            s8b b0 = *(const s8b*)(rb + brow0 * 512 + (off ^ bkey0));
            s8b b1 = *(const s8b*)(rb + brow1 * 512 + (off ^ bkey0));
            acc[0][0] = __builtin_amdgcn_mfma_f32_16x16x32_bf16(a0, b0, acc[0][0], 0, 0, 0);
            acc[0][1] = __builtin_amdgcn_mfma_f32_16x16x32_bf16(a0, b1, acc[0][1], 0, 0, 0);
            acc[1][0] = __builtin_amdgcn_mfma_f32_16x16x32_bf16(a1, b0, acc[1][0], 0, 0, 0);
            acc[1][1] = __builtin_amdgcn_mfma_f32_16x16x32_bf16(a1, b1, acc[1][1], 0, 0, 0);
        }

        float um[2], us[2];
        #pragma unroll
        for (int u = 0; u < 2; u++) {
            float vals[8];
            #pragma unroll
            for (int s = 0; s < 2; s++) {
                #pragma unroll
                for (int q = 0; q < 4; q++) {
                    int vloc = wv * 32 + s * 16 + lhi * 4 + q;
                    int vglob = v0r + vloc;
                    float logit = acc[s][u][q] + ebl[vloc];
                    bool valid = vglob < VV;
                    if (valid)
                        emitT[(size_t)vglob * CC + (c0 + wc * 32 + u * 16 + llo)] = f2bf(logit);
                    vals[s * 4 + q] = valid ? logit : -1e30f;
                }
            }
            float m = vals[0];
            #pragma unroll
            for (int e = 1; e < 8; e++) m = fmaxf(m, vals[e]);
            float ss = 0.f;
            #pragma unroll
            for (int e = 0; e < 8; e++) ss += __expf(vals[e] - m);
            #pragma unroll
            for (int o = 16; o < 64; o <<= 1) {
                float m2 = __shfl_xor(m, o);
                float s2 = __shfl_xor(ss, o);
                float nm = fmaxf(m, m2);
                ss = ss * __expf(m - nm) + s2 * __expf(m2 - nm);
                m = nm;
            }
            um[u] = m; us[u] = ss;
        }
        if (l < 16) {
            #pragma unroll
            for (int u = 0; u < 2; u++) {
                wlse[w][u][l][0] = um[u];
                wlse[w][u][l][1] = us[u];
            }
        }
        __syncthreads();
        if (th < 64) {
            int wc2 = th >> 5, u2 = (th >> 4) & 1, ll2 = th & 15;
            float m1 = wlse[2 * wc2][u2][ll2][0], s1 = wlse[2 * wc2][u2][ll2][1];
            float m2 = wlse[2 * wc2 + 1][u2][ll2][0], s2 = wlse[2 * wc2 + 1][u2][ll2][1];
            float nm = fmaxf(m1, m2);
            float ns = s1 * __expf(m1 - nm) + s2 * __expf(m2 - nm);
            float fm = fmaxf(rM, nm);
            rS = rS * __expf(rM - fm) + ns * __expf(nm - fm);
            rM = fm;
        }
    }
    if (th < 64) {
        epart2[((size_t)vb * CC + c0 + th) * 2]     = rM;
        epart2[((size_t)vb * CC + c0 + th) * 2 + 1] = rS;
    }
}

// ---------------- combine epart2 -> lse[c] ----------------
__global__ __launch_bounds__(256) void k_lse(const float* __restrict__ epart2,
                                             float* __restrict__ lse)
{
    int c = blockIdx.x * 256 + threadIdx.x;
    float M = -1e30f, S = 0.f;
    for (int vb = 0; vb < NVB; vb++) {
        float m  = epart2[((size_t)vb * CC + c) * 2];
        float s2 = epart2[((size_t)vb * CC + c) * 2 + 1];
        float nm = fmaxf(M, m);
        S = S * __expf(M - nm) + s2 * __expf(m - nm);
        M = nm;
    }
    lse[c] = M + __logf(S);
}

// load 8x16B coherent chunks of v[tslot] (this thread's share), sentinel-retry,
// then stage into swizzled LDS. Loads+waitcnt kept adjacent (no pipelining across
// other code) so regalloc can't spill pending asm outputs.
__device__ __forceinline__ void load_stage(const unsigned short* vbuf_t, int th, char* vl)
{
    const unsigned short* sb = vbuf_t + th * 8;
    s8b ch[8];
    #pragma unroll
    for (int c = 0; c < 8; c++)
        asm volatile("global_load_dwordx4 %0, %1, off sc0 sc1"
                     : "=v"(ch[c]) : "v"(sb + c * 2048));
    asm volatile("s_waitcnt vmcnt(0)" ::: "memory");
    __builtin_amdgcn_sched_barrier(0);
    for (;;) {
        unsigned int miss = 0u;
        #pragma unroll
        for (int c = 0; c < 8; c++) {
            u32x4 d = __builtin_bit_cast(u32x4, ch[c]);
            if (d[0] == 0xFFFFFFFFu || d[1] == 0xFFFFFFFFu ||
                d[2] == 0xFFFFFFFFu || d[3] == 0xFFFFFFFFu) miss |= 1u << c;
        }
        if (!__any(miss != 0u)) break;
        #pragma unroll
        for (int c = 0; c < 8; c++)
            if (miss & (1u << c))
                asm volatile("global_load_dwordx4 %0, %1, off sc0 sc1"
                             : "=v"(ch[c]) : "v"(sb + c * 2048));
        asm volatile("s_waitcnt vmcnt(0)" ::: "memory");
        __builtin_amdgcn_sched_barrier(0);
    }
    #pragma unroll
    for (int c = 0; c < 8; c++) {
        int ow = c * 4096 + th * 16;
        *(s8b*)(vl + (ow ^ (((ow >> 11) & 7) << 4))) = ch[c];
    }
}

// ---------------- forward scan: sentinel data-poll + LDS broadcast + ones-MFMA ----------------
// R8-proven structure; emission probs computed inline as exp(logit - lse_j).
__global__ void __launch_bounds__(256, 1) k_fwd(
    const unsigned short* __restrict__ PB,    // [1024 j][1024 i] bf16
    const unsigned short* __restrict__ emitT, // [V][1024 c] bf16 LOGITS
    const float* __restrict__ lse,            // [1024]
    const float* __restrict__ slog,
    const int* __restrict__ text,
    unsigned short* vbuf,                     // [TT][NN][CC] bf16, sentinel-armed
    float* __restrict__ outp)
{
    const int blk = blockIdx.x;
    const int th = threadIdx.x;
    const int w = th >> 6, l = th & 63;
    const int lhi = l >> 4, llo = l & 15;
    const int jglob = blk * 64 + w * 16 + llo;

    __shared__ int toks[NN * TT];                              // 16 KB
    __shared__ __align__(16) unsigned short vlds[NN * CC];     // 32 KB staged v
    __shared__ __align__(16) unsigned short vtile[16][72];     // publish staging (padded)
    __shared__ float swk[4];
    __shared__ float fin[16];

    for (int i = th; i < NN * TT; i += 256) toks[i] = text[i];

    // B fragments: wave's 16 j-columns, K=1024 -> 32 tiles resident in regs
    s8b bfr[32];
    {
        const unsigned short* pbj = PB + (size_t)jglob * CC + lhi * 8;
        #pragma unroll
        for (int kt = 0; kt < 32; kt++)
            bfr[kt] = *(const s8b*)(pbj + kt * 32);
    }
    s8b ones;
    #pragma unroll
    for (int e = 0; e < 8; e++) ones[e] = (short)0x3F80;   // bf16 1.0

    const float lse_j = lse[jglob];

    // block-wide LSE of slog
    float x0 = slog[th], x1 = slog[th + 256], x2 = slog[th + 512], x3 = slog[th + 768];
    float mw = fmaxf(fmaxf(x0, x1), fmaxf(x2, x3));
    #pragma unroll
    for (int o = 32; o; o >>= 1) mw = fmaxf(mw, __shfl_xor(mw, o));
    __syncthreads();   // toks ready
    if (l == 0) swk[w] = mw;
    __syncthreads();
    float gm = fmaxf(fmaxf(swk[0], swk[1]), fmaxf(swk[2], swk[3]));
    __syncthreads();
    float e4 = __expf(x0 - gm) + __expf(x1 - gm) + __expf(x2 - gm) + __expf(x3 - gm);
    #pragma unroll
    for (int o = 32; o; o >>= 1) e4 += __shfl_xor(e4, o);
    if (l == 0) swk[w] = e4;
    __syncthreads();
    float slse = gm + __logf(swk[0] + swk[1] + swk[2] + swk[3]);
    __syncthreads();

    // ---- t = 0: v0 = p0 * e0 for this block's 64 states, publish canonical chunks ----
    if (th < 64) {
        int jj = blk * 64 + th;
        float p0 = __expf(slog[jj] - slse);
        float lsej = lse[jj];
        #pragma unroll
        for (int n = 0; n < 16; n++)
            vtile[n][th] = f2bf(p0 * __expf(bf2f(emitT[(size_t)toks[n * TT] * CC + jj]) - lsej));
    }
    __syncthreads();
    if (th < 128) {
        int n = th >> 3, seg = th & 7;
        s8b val = *(const s8b*)&vtile[n][seg * 8];
        unsigned short* dst = vbuf + (size_t)n * CC + blk * 64 + seg * 8;
        asm volatile("global_store_dwordx4 %0, %1, off sc0 sc1" :: "v"(dst), "v"(val) : "memory");
    }

    float logaccq[4] = {0.f, 0.f, 0.f, 0.f};
    char* vl = (char*)vlds;
    const int rkey = (llo & 7) << 4;
    const int rbase = llo * 2048 + lhi * 16;

    for (int t = 1; t < TT; t++) {
        // emission-logit gather for this step (cached, read-only) -> prob inline
        float epf[4];
        #pragma unroll
        for (int q = 0; q < 4; q++)
            epf[q] = __expf(bf2f(emitT[(size_t)toks[(lhi * 4 + q) * TT + t] * CC + jglob]) - lse_j);

        // coherent load + sentinel retry + LDS stage of full v[t-1]
        load_stage(vbuf + (size_t)(t - 1) * (NN * CC), th, vl);
        __syncthreads();

        // MFMA: main chain (4-deep) + ones-chain (2-deep) for row sums S_n
        f32x4 ac0 = {0,0,0,0}, ac1 = {0,0,0,0}, ac2 = {0,0,0,0}, ac3 = {0,0,0,0};
        f32x4 ao0 = {0,0,0,0}, ao1 = {0,0,0,0};
        #pragma unroll
        for (int kt = 0; kt < 32; kt += 4) {
            s8b a0 = *(const s8b*)(vl + ((rbase + (kt + 0) * 64) ^ rkey));
            s8b a1 = *(const s8b*)(vl + ((rbase + (kt + 1) * 64) ^ rkey));
            s8b a2 = *(const s8b*)(vl + ((rbase + (kt + 2) * 64) ^ rkey));
            s8b a3 = *(const s8b*)(vl + ((rbase + (kt + 3) * 64) ^ rkey));
            ac0 = __builtin_amdgcn_mfma_f32_16x16x32_bf16(a0, bfr[kt + 0], ac0, 0, 0, 0);
            ao0 = __builtin_amdgcn_mfma_f32_16x16x32_bf16(a0, ones,        ao0, 0, 0, 0);
            ac1 = __builtin_amdgcn_mfma_f32_16x16x32_bf16(a1, bfr[kt + 1], ac1, 0, 0, 0);
            ao1 = __builtin_amdgcn_mfma_f32_16x16x32_bf16(a1, ones,        ao1, 0, 0, 0);
            ac2 = __builtin_amdgcn_mfma_f32_16x16x32_bf16(a2, bfr[kt + 2], ac2, 0, 0, 0);
            ao0 = __builtin_amdgcn_mfma_f32_16x16x32_bf16(a2, ones,        ao0, 0, 0, 0);
            ac3 = __builtin_amdgcn_mfma_f32_16x16x32_bf16(a3, bfr[kt + 3], ac3, 0, 0, 0);
            ao1 = __builtin_amdgcn_mfma_f32_16x16x32_bf16(a3, ones,        ao1, 0, 0, 0);
        }
        f32x4 acc = (ac0 + ac1) + (ac2 + ac3);
        f32x4 aco = ao0 + ao1;   // aco[q] = S_{n=lhi*4+q} (all columns identical)

        // epilogue: scale by 1/S, emission multiply, stage for publish
        #pragma unroll
        for (int q = 0; q < 4; q++) {
            float S = aco[q];
            logaccq[q] += __logf(S);
            float vq = acc[q] * (1.0f / S) * epf[q];
            vtile[lhi * 4 + q][w * 16 + llo] = f2bf(vq);
        }
        __syncthreads();

        // publish: 128 lanes store 16B canonical chunks
        if (th < 128) {
            int n = th >> 3, seg = th & 7;
            s8b val = *(const s8b*)&vtile[n][seg * 8];
            unsigned short* dst = vbuf + (size_t)t * (NN * CC) + (size_t)n * CC + blk * 64 + seg * 8;
            asm volatile("global_store_dwordx4 %0, %1, off sc0 sc1" :: "v"(dst), "v"(val) : "memory");
        }
    }

    // ---- final: block 0 loads v[255], computes S_255 via ones-MFMA, writes output ----
    if (blk == 0) {
        load_stage(vbuf + (size_t)255 * (NN * CC), th, vl);
        __syncthreads();
        f32x4 ao0 = {0,0,0,0}, ao1 = {0,0,0,0};
        #pragma unroll
        for (int kt = 0; kt < 32; kt += 2) {
            s8b a0 = *(const s8b*)(vl + ((rbase + (kt + 0) * 64) ^ rkey));
            s8b a1 = *(const s8b*)(vl + ((rbase + (kt + 1) * 64) ^ rkey));
            ao0 = __builtin_amdgcn_mfma_f32_16x16x32_bf16(a0, ones, ao0, 0, 0, 0);
            ao1 = __builtin_amdgcn_mfma_f32_16x16x32_bf16(a1, ones, ao1, 0, 0, 0);
        }
        f32x4 acoF = ao0 + ao1;
        if (w == 0 && llo == 0) {
            #pragma unroll
            for (int q = 0; q < 4; q++)
                fin[lhi * 4 + q] = logaccq[q] + __logf(acoF[q]);
        }
        __syncthreads();
        if (th == 0) {
            float tot = 0.f;
            for (int n = 0; n < 16; n++) tot += fin[n];
            outp[0] = tot;
        }
    }
}

extern "C" void kernel_launch(void* const* d_in, const int* in_sizes, int n_in,
                              void* d_out, int out_size, void* d_ws, size_t ws_size,
                              hipStream_t stream) {
    const int*   text      = (const int*)  d_in[0];
    const float* start_emb = (const float*)d_in[1];
    const float* sw1 = (const float*)d_in[2];
    const float* sb1 = (const float*)d_in[3];
    const float* sw2 = (const float*)d_in[4];
    const float* sb2 = (const float*)d_in[5];
    const float* sw3 = (const float*)d_in[6];
    const float* sb3 = (const float*)d_in[7];
    const float* state_emb = (const float*)d_in[8];
    const float* tw1 = (const float*)d_in[9];
    const float* tb1 = (const float*)d_in[10];
    const float* tw2 = (const float*)d_in[11];
    const float* tb2 = (const float*)d_in[12];
    const float* tw3 = (const float*)d_in[13];
    const float* tb3 = (const float*)d_in[14];
    const float* pre_emb = (const float*)d_in[15];
    const float* ew1 = (const float*)d_in[16];
    const float* eb1 = (const float*)d_in[17];
    const float* ew2 = (const float*)d_in[18];
    const float* eb2 = (const float*)d_in[19];
    const float* ew3 = (const float*)d_in[20];
    const float* eb3 = (const float*)d_in[21];

    char* wsp = (char*)d_ws;
    // layout (bytes):
    //   PB     [0, 2 MiB)
    //   emitT  [2 MiB, 22,577,152)
    //   res_s  [2 MiB, 3 MiB)    \ overlay emitT head: dead before k_emitg writes
    //   res_t  [3 MiB, 4 MiB)    /
    //   res_e  [22,577,152, 23,625,728)
    //   slog   [23,625,728, +4 KiB)
    //   lse    [23,629,824, +4 KiB)
    //   epart2 [23,633,920, +320 KiB)
    //   vbuf   [23 MiB, 31 MiB) sentinel-armed
    unsigned short* PB    = (unsigned short*)(wsp);
    unsigned short* emitT = (unsigned short*)(wsp + ((size_t)2 << 20));
    float* res_s = (float*)(wsp + ((size_t)2 << 20));
    float* res_t = (float*)(wsp + ((size_t)3 << 20));
    float* res_e = (float*)(wsp + 22577152u);
    float* slog  = (float*)(wsp + 23625728u);
    float* lse   = (float*)(wsp + 23629824u);
    float* epart2= (float*)(wsp + 23633920u);
    unsigned short* vbuf = (unsigned short*)(wsp + ((size_t)23 << 20));
    float* outp  = (float*)d_out;

    if (ws_size < ((size_t)31 << 20)) return;  // leaves poison -> visible failure

    hipMemsetAsync(vbuf, 0xFF, (size_t)TT * NN * CC * sizeof(unsigned short), stream);

    ResArgs3 ra;
    ra.a[0] = { start_emb, sw1, sb1, sw2, sb2, res_s };
    ra.a[1] = { state_emb, tw1, tb1, tw2, tb2, res_t };
    ra.a[2] = { pre_emb,   ew1, eb1, ew2, eb2, res_e };

    hipLaunchKernelGGL(k_res,   dim3(64, 3),   dim3(256), 0, stream, ra);
    hipLaunchKernelGGL(k_slog,  dim3(4),       dim3(256), 0, stream, res_s, sw3, sb3, slog);
    hipLaunchKernelGGL(k_pt,    dim3(256),     dim3(256), 0, stream, res_t, tw3, tb3, PB);
    hipLaunchKernelGGL(k_emitg, dim3(NVB, 16), dim3(256), 0, stream, res_e, ew3, eb3, emitT, epart2);
    hipLaunchKernelGGL(k_lse,   dim3(4),       dim3(256), 0, stream, epart2, lse);
    hipLaunchKernelGGL(k_fwd,   dim3(NB),      dim3(256), 0, stream,
                       PB, emitT, lse, slog, text, vbuf, outp);
}

// Round 11
// 913.776 us; speedup vs baseline: 1.4138x; 1.0481x over previous
//
#include <hip/hip_runtime.h>
#include <hip/hip_bf16.h>
#include <cstddef>

#define CC 1024   // states
#define HH 256    // hidden
#define VV 10000  // vocab
#define NN 16     // batch
#define TT 256    // time
#define NB 16     // blocks in k_fwd
#define NVB 40    // v-tiles in k_emitg

typedef __attribute__((ext_vector_type(8))) short s8b;
typedef __attribute__((ext_vector_type(4))) float f32x4;
typedef __attribute__((ext_vector_type(4))) unsigned int u32x4;

__device__ __forceinline__ unsigned short f2bf(float f) {
    unsigned int b = __builtin_bit_cast(unsigned int, f);
    b += 0x7FFFu + ((b >> 16) & 1u);
    return (unsigned short)(b >> 16);
}
__device__ __forceinline__ float bf2f(unsigned short u) {
    return __builtin_bit_cast(float, ((unsigned int)u) << 16);
}

// ---------------- fused prep: res_e MLP | slog (res+dot) | PB (res+softmax) | vbuf arm ----------------
// roles by blockIdx.x: [0,64) res_e rows; [64,128) slog rows; [128,384) transition rows; [384,448) memset
__global__ __launch_bounds__(256) void k_prep(
    const float* __restrict__ start_emb,
    const float* __restrict__ sw1, const float* __restrict__ sb1,
    const float* __restrict__ sw2, const float* __restrict__ sb2,
    const float* __restrict__ sw3, const float* __restrict__ sb3,
    const float* __restrict__ state_emb,
    const float* __restrict__ tw1, const float* __restrict__ tb1,
    const float* __restrict__ tw2, const float* __restrict__ tb2,
    const float* __restrict__ tw3, const float* __restrict__ tb3,
    const float* __restrict__ pre_emb,
    const float* __restrict__ ew1, const float* __restrict__ eb1,
    const float* __restrict__ ew2, const float* __restrict__ eb2,
    float* __restrict__ res_e, float* __restrict__ slog,
    unsigned short* __restrict__ PB, unsigned short* __restrict__ vbuf)
{
    __shared__ float xs[256][24];
    __shared__ float hs[256][24];
    const int th = threadIdx.x;
    const int b = blockIdx.x;

    if (b < 64) {
        // ---- role A: res_e = residual MLP of pre_emb, 16 rows ----
        const int r0 = b * 16;
        #pragma unroll
        for (int k = 0; k < 16; k++) xs[th][k] = pre_emb[(size_t)(r0 + k) * HH + th];
        __syncthreads();
        float acc[16];
        float b1v = eb1[th];
        #pragma unroll
        for (int r = 0; r < 16; r++) acc[r] = b1v;
        for (int h = 0; h < HH; h++) {
            float w = ew1[(size_t)h * HH + th];
            #pragma unroll
            for (int r = 0; r < 16; r++) acc[r] = fmaf(xs[h][r], w, acc[r]);
        }
        #pragma unroll
        for (int r = 0; r < 16; r++) hs[th][r] = fmaxf(acc[r], 0.f);
        __syncthreads();
        float b2v = eb2[th];
        #pragma unroll
        for (int r = 0; r < 16; r++) acc[r] = b2v;
        for (int h = 0; h < HH; h++) {
            float w = ew2[(size_t)h * HH + th];
            #pragma unroll
            for (int r = 0; r < 16; r++) acc[r] = fmaf(hs[h][r], w, acc[r]);
        }
        #pragma unroll
        for (int r = 0; r < 16; r++) {
            size_t idx = (size_t)(r0 + r) * HH + th;
            res_e[idx] = fmaxf(acc[r], 0.f) + pre_emb[idx];
        }
    } else if (b < 128) {
        // ---- role B: slog = (res MLP of start_emb) @ sw3 + sb3, 16 rows ----
        const int r0 = (b - 64) * 16;
        #pragma unroll
        for (int k = 0; k < 16; k++) xs[th][k] = start_emb[(size_t)(r0 + k) * HH + th];
        __syncthreads();
        float acc[16];
        float b1v = sb1[th];
        #pragma unroll
        for (int r = 0; r < 16; r++) acc[r] = b1v;
        for (int h = 0; h < HH; h++) {
            float w = sw1[(size_t)h * HH + th];
            #pragma unroll
            for (int r = 0; r < 16; r++) acc[r] = fmaf(xs[h][r], w, acc[r]);
        }
        #pragma unroll
        for (int r = 0; r < 16; r++) hs[th][r] = fmaxf(acc[r], 0.f);
        __syncthreads();
        float b2v = sb2[th];
        #pragma unroll
        for (int r = 0; r < 16; r++) acc[r] = b2v;
        for (int h = 0; h < HH; h++) {
            float w = sw2[(size_t)h * HH + th];
            #pragma unroll
            for (int r = 0; r < 16; r++) acc[r] = fmaf(hs[h][r], w, acc[r]);
        }
        float accf[16];
        #pragma unroll
        for (int r = 0; r < 16; r++)
            accf[r] = fmaxf(acc[r], 0.f) + start_emb[(size_t)(r0 + r) * HH + th];
        __syncthreads();   // hs reads done before reusing hs as ws
        float* ws = (float*)&hs[0][0];
        float wv = sw3[th];
        const int wq = th >> 6, ln = th & 63;
        #pragma unroll
        for (int r = 0; r < 16; r++) {
            float p = accf[r] * wv;
            #pragma unroll
            for (int o = 32; o; o >>= 1) p += __shfl_xor(p, o);
            if (ln == 0) ws[wq * 16 + r] = p;
        }
        __syncthreads();
        if (th < 16) slog[r0 + th] = ws[th] + ws[16 + th] + ws[32 + th] + ws[48 + th] + sb3[0];
    } else if (b < 384) {
        // ---- role C: transition rows r0..r0+4: res MLP + logits + row softmax -> PB[j][i] ----
        const int r0c = (b - 128) * 4;
        float (*rs)[256] = (float (*)[256])&xs[0][0];
        float (*h2)[256] = (float (*)[256])(&xs[0][0] + 1024);
        float* sred = (float*)&hs[0][0];
        for (int k = 0; k < 4; k++) rs[k][th] = state_emb[(size_t)(r0c + k) * HH + th];
        __syncthreads();
        float a1[4];
        {
            float b1v = tb1[th];
            #pragma unroll
            for (int r = 0; r < 4; r++) a1[r] = b1v;
            for (int h = 0; h < HH; h++) {
                float w = tw1[(size_t)h * HH + th];
                #pragma unroll
                for (int r = 0; r < 4; r++) a1[r] = fmaf(rs[r][h], w, a1[r]);
            }
        }
        #pragma unroll
        for (int r = 0; r < 4; r++) h2[r][th] = fmaxf(a1[r], 0.f);
        __syncthreads();
        float a2[4];
        {
            float b2v = tb2[th];
            #pragma unroll
            for (int r = 0; r < 4; r++) a2[r] = b2v;
            for (int h = 0; h < HH; h++) {
                float w = tw2[(size_t)h * HH + th];
                #pragma unroll
                for (int r = 0; r < 4; r++) a2[r] = fmaf(h2[r][h], w, a2[r]);
            }
        }
        #pragma unroll
        for (int r = 0; r < 4; r++) rs[r][th] = fmaxf(a2[r], 0.f) + rs[r][th];
        __syncthreads();
        // logits + softmax (proven k_pt body)
        float acc[4][4];
        #pragma unroll
        for (int r = 0; r < 4; r++)
            #pragma unroll
            for (int q = 0; q < 4; q++) acc[r][q] = tb3[th + q * 256];
        for (int h = 0; h < HH; h++) {
            float w0 = tw3[(size_t)h * CC + th];
            float w1 = tw3[(size_t)h * CC + th + 256];
            float w2 = tw3[(size_t)h * CC + th + 512];
            float w3 = tw3[(size_t)h * CC + th + 768];
            #pragma unroll
            for (int r = 0; r < 4; r++) {
                float xv = rs[r][h];
                acc[r][0] = fmaf(xv, w0, acc[r][0]);
                acc[r][1] = fmaf(xv, w1, acc[r][1]);
                acc[r][2] = fmaf(xv, w2, acc[r][2]);
                acc[r][3] = fmaf(xv, w3, acc[r][3]);
            }
        }
        for (int r = 0; r < 4; r++) {
            float m = fmaxf(fmaxf(acc[r][0], acc[r][1]), fmaxf(acc[r][2], acc[r][3]));
            sred[th] = m; __syncthreads();
            for (int off = 128; off > 0; off >>= 1) { if (th < off) sred[th] = fmaxf(sred[th], sred[th + off]); __syncthreads(); }
            float rm = sred[0]; __syncthreads();
            float ssum = __expf(acc[r][0] - rm) + __expf(acc[r][1] - rm) + __expf(acc[r][2] - rm) + __expf(acc[r][3] - rm);
            sred[th] = ssum; __syncthreads();
            for (int off = 128; off > 0; off >>= 1) { if (th < off) sred[th] += sred[th + off]; __syncthreads(); }
            float inv = 1.0f / sred[0]; __syncthreads();
            #pragma unroll
            for (int q = 0; q < 4; q++) {
                float p = __expf(acc[r][q] - rm) * inv;
                PB[(size_t)(th + q * 256) * CC + (r0c + r)] = f2bf(p);   // [j][i]
            }
        }
    } else {
        // ---- role D: arm vbuf sentinels (8 MiB of 0xFF) ----
        const int blk = b - 384;
        unsigned long long* dst = (unsigned long long*)vbuf + (size_t)blk * 16384;
        for (int i = th; i < 16384; i += 256) dst[i] = 0xFFFFFFFFFFFFFFFFull;
    }
}

// ---------------- emission logits via MFMA GEMM + fused LSE partials ----------------
__global__ __launch_bounds__(256) void k_emitg(const float* __restrict__ res_e,
                                               const float* __restrict__ ew3,
                                               const float* __restrict__ eb3,
                                               unsigned short* __restrict__ emitT,
                                               float* __restrict__ epart2)
{
    const int vb = blockIdx.x, c0 = blockIdx.y * 64;
    const int th = threadIdx.x;
    const int w = th >> 6, l = th & 63;
    const int lhi = l >> 4, llo = l & 15;
    const int wv = w & 1, wc = w >> 1;

    __shared__ __align__(16) unsigned short ewT[64 * 256];
    __shared__ __align__(16) unsigned short rsb[64 * 256];
    __shared__ float ebl[64];
    __shared__ float wlse[4][2][16][2];

    {
        char* base = (char*)rsb;
        #pragma unroll
        for (int i = 0; i < 8; i++) {
            int g = i * 2048 + th * 8;
            int row = g >> 8, h0 = g & 255;
            const float* src = res_e + (size_t)(c0 + row) * HH + h0;
            float4 f0 = *(const float4*)(src);
            float4 f1 = *(const float4*)(src + 4);
            s8b pk;
            pk[0] = (short)f2bf(f0.x); pk[1] = (short)f2bf(f0.y);
            pk[2] = (short)f2bf(f0.z); pk[3] = (short)f2bf(f0.w);
            pk[4] = (short)f2bf(f1.x); pk[5] = (short)f2bf(f1.y);
            pk[6] = (short)f2bf(f1.z); pk[7] = (short)f2bf(f1.w);
            *(s8b*)(base + row * 512 + ((h0 * 2) ^ ((row & 7) << 4))) = pk;
        }
    }

    float rM = -1e30f, rS = 0.f;

    for (int r = 0; r < 4; r++) {
        const int v0r = vb * 256 + r * 64;
        __syncthreads();
        {
            int tv = th & 63;
            char* base = (char*)ewT;
            int rowoff = tv * 512;
            int key = (tv & 7) << 4;
            int vglob = v0r + tv;
            bool valid = vglob < VV;
            #pragma unroll 8
            for (int i = 0; i < 64; i++) {
                int h = (th >> 6) + i * 4;
                float x = valid ? ew3[(size_t)h * VV + vglob] : 0.f;
                *(unsigned short*)(base + rowoff + ((h * 2) ^ key)) = f2bf(x);
            }
        }
        if (th < 64) ebl[th] = (v0r + th < VV) ? eb3[v0r + th] : 0.f;
        __syncthreads();

        f32x4 acc[2][2] = {{{0,0,0,0},{0,0,0,0}},{{0,0,0,0},{0,0,0,0}}};
        const char* ea = (const char*)ewT;
        const char* rb = (const char*)rsb;
        const int arow0 = wv * 32 + llo, arow1 = wv * 32 + 16 + llo;
        const int brow0 = wc * 32 + llo, brow1 = wc * 32 + 16 + llo;
        const int akey0 = (arow0 & 7) << 4;
        const int bkey0 = (brow0 & 7) << 4;
        #pragma unroll
        for (int kt = 0; kt < 8; kt++) {
            int off = kt * 64 + lhi * 16;
            s8b a0 = *(const s8b*)(ea + arow0 * 512 + (off ^ akey0));
            s8b a1 = *(const s8b*)(ea + arow1 * 512 + (off ^ akey0));
            s8b b0 = *(const s8b*)(rb + brow0 * 512 + (off ^ bkey0));
            s8b b1 = *(const s8b*)(rb + brow1 * 512 + (off ^ bkey0));
            acc[0][0] = __builtin_amdgcn_mfma_f32_16x16x32_bf16(a0, b0, acc[0][0], 0, 0, 0);
            acc[0][1] = __builtin_amdgcn_mfma_f32_16x16x32_bf16(a0, b1, acc[0][1], 0, 0, 0);
            acc[1][0] = __builtin_amdgcn_mfma_f32_16x16x32_bf16(a1, b0, acc[1][0], 0, 0, 0);
            acc[1][1] = __builtin_amdgcn_mfma_f32_16x16x32_bf16(a1, b1, acc[1][1], 0, 0, 0);
        }

        float um[2], us[2];
        #pragma unroll
        for (int u = 0; u < 2; u++) {
            float vals[8];
            #pragma unroll
            for (int s = 0; s < 2; s++) {
                #pragma unroll
                for (int q = 0; q < 4; q++) {
                    int vloc = wv * 32 + s * 16 + lhi * 4 + q;
                    int vglob = v0r + vloc;
                    float logit = acc[s][u][q] + ebl[vloc];
                    bool valid = vglob < VV;
                    if (valid)
                        emitT[(size_t)vglob * CC + (c0 + wc * 32 + u * 16 + llo)] = f2bf(logit);
                    vals[s * 4 + q] = valid ? logit : -1e30f;
                }
            }
            float m = vals[0];
            #pragma unroll
            for (int e = 1; e < 8; e++) m = fmaxf(m, vals[e]);
            float ss = 0.f;
            #pragma unroll
            for (int e = 0; e < 8; e++) ss += __expf(vals[e] - m);
            #pragma unroll
            for (int o = 16; o < 64; o <<= 1) {
                float m2 = __shfl_xor(m, o);
                float s2 = __shfl_xor(ss, o);
                float nm = fmaxf(m, m2);
                ss = ss * __expf(m - nm) + s2 * __expf(m2 - nm);
                m = nm;
            }
            um[u] = m; us[u] = ss;
        }
        if (l < 16) {
            #pragma unroll
            for (int u = 0; u < 2; u++) {
                wlse[w][u][l][0] = um[u];
                wlse[w][u][l][1] = us[u];
            }
        }
        __syncthreads();
        if (th < 64) {
            int wc2 = th >> 5, u2 = (th >> 4) & 1, ll2 = th & 15;
            float m1 = wlse[2 * wc2][u2][ll2][0], s1 = wlse[2 * wc2][u2][ll2][1];
            float m2 = wlse[2 * wc2 + 1][u2][ll2][0], s2 = wlse[2 * wc2 + 1][u2][ll2][1];
            float nm = fmaxf(m1, m2);
            float ns = s1 * __expf(m1 - nm) + s2 * __expf(m2 - nm);
            float fm = fmaxf(rM, nm);
            rS = rS * __expf(rM - fm) + ns * __expf(nm - fm);
            rM = fm;
        }
    }
    if (th < 64) {
        epart2[((size_t)vb * CC + c0 + th) * 2]     = rM;
        epart2[((size_t)vb * CC + c0 + th) * 2 + 1] = rS;
    }
}

// load 8x16B coherent chunks of v[tslot] (this thread's share), sentinel-retry,
// then stage into swizzled LDS.
__device__ __forceinline__ void load_stage(const unsigned short* vbuf_t, int th, char* vl)
{
    const unsigned short* sb = vbuf_t + th * 8;
    s8b ch[8];
    #pragma unroll
    for (int c = 0; c < 8; c++)
        asm volatile("global_load_dwordx4 %0, %1, off sc0 sc1"
                     : "=v"(ch[c]) : "v"(sb + c * 2048));
    asm volatile("s_waitcnt vmcnt(0)" ::: "memory");
    __builtin_amdgcn_sched_barrier(0);
    for (;;) {
        unsigned int miss = 0u;
        #pragma unroll
        for (int c = 0; c < 8; c++) {
            u32x4 d = __builtin_bit_cast(u32x4, ch[c]);
            if (d[0] == 0xFFFFFFFFu || d[1] == 0xFFFFFFFFu ||
                d[2] == 0xFFFFFFFFu || d[3] == 0xFFFFFFFFu) miss |= 1u << c;
        }
        if (!__any(miss != 0u)) break;
        #pragma unroll
        for (int c = 0; c < 8; c++)
            if (miss & (1u << c))
                asm volatile("global_load_dwordx4 %0, %1, off sc0 sc1"
                             : "=v"(ch[c]) : "v"(sb + c * 2048));
        asm volatile("s_waitcnt vmcnt(0)" ::: "memory");
        __builtin_amdgcn_sched_barrier(0);
    }
    #pragma unroll
    for (int c = 0; c < 8; c++) {
        int ow = c * 4096 + th * 16;
        *(s8b*)(vl + (ow ^ (((ow >> 11) & 7) << 4))) = ch[c];
    }
}

// ---------------- forward scan (R10-proven) + fused per-block lse prologue ----------------
__global__ void __launch_bounds__(256, 1) k_fwd(
    const unsigned short* __restrict__ PB,    // [1024 j][1024 i] bf16
    const unsigned short* __restrict__ emitT, // [V][1024 c] bf16 LOGITS
    const float* __restrict__ epart2,         // [40 vb][1024 c][2]
    const float* __restrict__ slog,
    const int* __restrict__ text,
    unsigned short* vbuf,                     // [TT][NN][CC] bf16, sentinel-armed
    float* __restrict__ outp)
{
    const int blk = blockIdx.x;
    const int th = threadIdx.x;
    const int w = th >> 6, l = th & 63;
    const int lhi = l >> 4, llo = l & 15;
    const int jglob = blk * 64 + w * 16 + llo;

    __shared__ int toks[NN * TT];                              // 16 KB
    __shared__ __align__(16) unsigned short vlds[NN * CC];     // 32 KB staged v
    __shared__ __align__(16) unsigned short vtile[16][72];
    __shared__ float swk[4];
    __shared__ float fin[16];
    __shared__ float lsej[64];

    for (int i = th; i < NN * TT; i += 256) toks[i] = text[i];

    // B fragments resident in regs
    s8b bfr[32];
    {
        const unsigned short* pbj = PB + (size_t)jglob * CC + lhi * 8;
        #pragma unroll
        for (int kt = 0; kt < 32; kt++)
            bfr[kt] = *(const s8b*)(pbj + kt * 32);
    }
    s8b ones;
    #pragma unroll
    for (int e = 0; e < 8; e++) ones[e] = (short)0x3F80;   // bf16 1.0

    // fused lse for this block's 64 j (vlds reused as scratch)
    {
        float* mm  = (float*)vlds;         // 256
        float* ssm = mm + 256;             // 256
        int cl = blk * 64 + (th & 63);
        int v0 = (th >> 6) * 10;
        float M = -1e30f, S = 0.f;
        for (int vb = v0; vb < v0 + 10; vb++) {
            float m  = epart2[((size_t)vb * CC + cl) * 2];
            float s2 = epart2[((size_t)vb * CC + cl) * 2 + 1];
            float nm = fmaxf(M, m);
            S = S * __expf(M - nm) + s2 * __expf(m - nm);
            M = nm;
        }
        mm[th] = M; ssm[th] = S;
        __syncthreads();
        if (th < 64) {
            float Mf = -1e30f, Sf = 0.f;
            #pragma unroll
            for (int q = 0; q < 4; q++) {
                float m = mm[q * 64 + th], s2 = ssm[q * 64 + th];
                float nm = fmaxf(Mf, m);
                Sf = Sf * __expf(Mf - nm) + s2 * __expf(m - nm);
                Mf = nm;
            }
            lsej[th] = Mf + __logf(Sf);
        }
        __syncthreads();
    }
    const float lse_j = lsej[w * 16 + llo];

    // block-wide LSE of slog
    float x0 = slog[th], x1 = slog[th + 256], x2 = slog[th + 512], x3 = slog[th + 768];
    float mw = fmaxf(fmaxf(x0, x1), fmaxf(x2, x3));
    #pragma unroll
    for (int o = 32; o; o >>= 1) mw = fmaxf(mw, __shfl_xor(mw, o));
    __syncthreads();
    if (l == 0) swk[w] = mw;
    __syncthreads();
    float gm = fmaxf(fmaxf(swk[0], swk[1]), fmaxf(swk[2], swk[3]));
    __syncthreads();
    float e4 = __expf(x0 - gm) + __expf(x1 - gm) + __expf(x2 - gm) + __expf(x3 - gm);
    #pragma unroll
    for (int o = 32; o; o >>= 1) e4 += __shfl_xor(e4, o);
    if (l == 0) swk[w] = e4;
    __syncthreads();
    float slse = gm + __logf(swk[0] + swk[1] + swk[2] + swk[3]);
    __syncthreads();

    // ---- t = 0 ----
    if (th < 64) {
        int jj = blk * 64 + th;
        float p0 = __expf(slog[jj] - slse);
        float lsej_c = lsej[th];
        #pragma unroll
        for (int n = 0; n < 16; n++)
            vtile[n][th] = f2bf(p0 * __expf(bf2f(emitT[(size_t)toks[n * TT] * CC + jj]) - lsej_c));
    }
    __syncthreads();
    if (th < 128) {
        int n = th >> 3, seg = th & 7;
        s8b val = *(const s8b*)&vtile[n][seg * 8];
        unsigned short* dst = vbuf + (size_t)n * CC + blk * 64 + seg * 8;
        asm volatile("global_store_dwordx4 %0, %1, off sc0 sc1" :: "v"(dst), "v"(val) : "memory");
    }

    float logaccq[4] = {0.f, 0.f, 0.f, 0.f};
    char* vl = (char*)vlds;
    const int rkey = (llo & 7) << 4;
    const int rbase = llo * 2048 + lhi * 16;

    for (int t = 1; t < TT; t++) {
        float epf[4];
        #pragma unroll
        for (int q = 0; q < 4; q++)
            epf[q] = __expf(bf2f(emitT[(size_t)toks[(lhi * 4 + q) * TT + t] * CC + jglob]) - lse_j);

        load_stage(vbuf + (size_t)(t - 1) * (NN * CC), th, vl);
        __syncthreads();

        f32x4 ac0 = {0,0,0,0}, ac1 = {0,0,0,0}, ac2 = {0,0,0,0}, ac3 = {0,0,0,0};
        f32x4 ao0 = {0,0,0,0}, ao1 = {0,0,0,0};
        #pragma unroll
        for (int kt = 0; kt < 32; kt += 4) {
            s8b a0 = *(const s8b*)(vl + ((rbase + (kt + 0) * 64) ^ rkey));
            s8b a1 = *(const s8b*)(vl + ((rbase + (kt + 1) * 64) ^ rkey));
            s8b a2 = *(const s8b*)(vl + ((rbase + (kt + 2) * 64) ^ rkey));
            s8b a3 = *(const s8b*)(vl + ((rbase + (kt + 3) * 64) ^ rkey));
            ac0 = __builtin_amdgcn_mfma_f32_16x16x32_bf16(a0, bfr[kt + 0], ac0, 0, 0, 0);
            ao0 = __builtin_amdgcn_mfma_f32_16x16x32_bf16(a0, ones,        ao0, 0, 0, 0);
            ac1 = __builtin_amdgcn_mfma_f32_16x16x32_bf16(a1, bfr[kt + 1], ac1, 0, 0, 0);
            ao1 = __builtin_amdgcn_mfma_f32_16x16x32_bf16(a1, ones,        ao1, 0, 0, 0);
            ac2 = __builtin_amdgcn_mfma_f32_16x16x32_bf16(a2, bfr[kt + 2], ac2, 0, 0, 0);
            ao0 = __builtin_amdgcn_mfma_f32_16x16x32_bf16(a2, ones,        ao0, 0, 0, 0);
            ac3 = __builtin_amdgcn_mfma_f32_16x16x32_bf16(a3, bfr[kt + 3], ac3, 0, 0, 0);
            ao1 = __builtin_amdgcn_mfma_f32_16x16x32_bf16(a3, ones,        ao1, 0, 0, 0);
        }
        f32x4 acc = (ac0 + ac1) + (ac2 + ac3);
        f32x4 aco = ao0 + ao1;

        #pragma unroll
        for (int q = 0; q < 4; q++) {
            float S = aco[q];
            logaccq[q] += __logf(S);
            float vq = acc[q] * (1.0f / S) * epf[q];
            vtile[lhi * 4 + q][w * 16 + llo] = f2bf(vq);
        }
        __syncthreads();

        if (th < 128) {
            int n = th >> 3, seg = th & 7;
            s8b val = *(const s8b*)&vtile[n][seg * 8];
            unsigned short* dst = vbuf + (size_t)t * (NN * CC) + (size_t)n * CC + blk * 64 + seg * 8;
            asm volatile("global_store_dwordx4 %0, %1, off sc0 sc1" :: "v"(dst), "v"(val) : "memory");
        }
    }

    // ---- final: block 0 loads v[255], S_255 via ones-MFMA, output ----
    if (blk == 0) {
        load_stage(vbuf + (size_t)255 * (NN * CC), th, vl);
        __syncthreads();
        f32x4 ao0 = {0,0,0,0}, ao1 = {0,0,0,0};
        #pragma unroll
        for (int kt = 0; kt < 32; kt += 2) {
            s8b a0 = *(const s8b*)(vl + ((rbase + (kt + 0) * 64) ^ rkey));
            s8b a1 = *(const s8b*)(vl + ((rbase + (kt + 1) * 64) ^ rkey));
            ao0 = __builtin_amdgcn_mfma_f32_16x16x32_bf16(a0, ones, ao0, 0, 0, 0);
            ao1 = __builtin_amdgcn_mfma_f32_16x16x32_bf16(a1, ones, ao1, 0, 0, 0);
        }
        f32x4 acoF = ao0 + ao1;
        if (w == 0 && llo == 0) {
            #pragma unroll
            for (int q = 0; q < 4; q++)
                fin[lhi * 4 + q] = logaccq[q] + __logf(acoF[q]);
        }
        __syncthreads();
        if (th == 0) {
            float tot = 0.f;
            for (int n = 0; n < 16; n++) tot += fin[n];
            outp[0] = tot;
        }
    }
}

extern "C" void kernel_launch(void* const* d_in, const int* in_sizes, int n_in,
                              void* d_out, int out_size, void* d_ws, size_t ws_size,
                              hipStream_t stream) {
    const int*   text      = (const int*)  d_in[0];
    const float* start_emb = (const float*)d_in[1];
    const float* sw1 = (const float*)d_in[2];
    const float* sb1 = (const float*)d_in[3];
    const float* sw2 = (const float*)d_in[4];
    const float* sb2 = (const float*)d_in[5];
    const float* sw3 = (const float*)d_in[6];
    const float* sb3 = (const float*)d_in[7];
    const float* state_emb = (const float*)d_in[8];
    const float* tw1 = (const float*)d_in[9];
    const float* tb1 = (const float*)d_in[10];
    const float* tw2 = (const float*)d_in[11];
    const float* tb2 = (const float*)d_in[12];
    const float* tw3 = (const float*)d_in[13];
    const float* tb3 = (const float*)d_in[14];
    const float* pre_emb = (const float*)d_in[15];
    const float* ew1 = (const float*)d_in[16];
    const float* eb1 = (const float*)d_in[17];
    const float* ew2 = (const float*)d_in[18];
    const float* eb2 = (const float*)d_in[19];
    const float* ew3 = (const float*)d_in[20];
    const float* eb3 = (const float*)d_in[21];

    char* wsp = (char*)d_ws;
    // layout (bytes):
    //   PB     [0, 2 MiB)
    //   emitT  [2 MiB, 22,577,152)
    //   res_e  [22,577,152, 23,625,728)
    //   slog   [23,625,728, +4 KiB)
    //   epart2 [23,633,920, +320 KiB)
    //   vbuf   [23 MiB, 31 MiB) sentinel-armed by k_prep role D
    unsigned short* PB    = (unsigned short*)(wsp);
    unsigned short* emitT = (unsigned short*)(wsp + ((size_t)2 << 20));
    float* res_e = (float*)(wsp + 22577152u);
    float* slog  = (float*)(wsp + 23625728u);
    float* epart2= (float*)(wsp + 23633920u);
    unsigned short* vbuf = (unsigned short*)(wsp + ((size_t)23 << 20));
    float* outp  = (float*)d_out;

    if (ws_size < ((size_t)31 << 20)) return;  // leaves poison -> visible failure

    hipLaunchKernelGGL(k_prep,  dim3(448),     dim3(256), 0, stream,
                       start_emb, sw1, sb1, sw2, sb2, sw3, sb3,
                       state_emb, tw1, tb1, tw2, tb2, tw3, tb3,
                       pre_emb,   ew1, eb1, ew2, eb2,
                       res_e, slog, PB, vbuf);
    hipLaunchKernelGGL(k_emitg, dim3(NVB, 16), dim3(256), 0, stream, res_e, ew3, eb3, emitT, epart2);
    hipLaunchKernelGGL(k_fwd,   dim3(NB),      dim3(256), 0, stream,
                       PB, emitT, epart2, slog, text, vbuf, outp);
}